// Round 3
// baseline (2105.166 us; speedup 1.0000x reference)
//
#include <hip/hip_runtime.h>
#include <cstddef>

// Problem constants (fixed by the reference): hidden=300, max_nb=6.
#define H 300
#define H4 75
#define MAXNB 6

// bf16 <-> fp32 helpers (bit-level, round-to-nearest-even)
__device__ __forceinline__ float bf2f(unsigned short u) {
    return __uint_as_float(((unsigned int)u) << 16);
}
__device__ __forceinline__ unsigned short f2bf(float f) {
    unsigned int u = __float_as_uint(f);
    u += 0x7FFFu + ((u >> 16) & 1u);
    return (unsigned short)(u >> 16);
}

// ---------------------------------------------------------------------------
// GEMM 1: inp = f_bonds @ W_i (store bf16 raw), msg = relu(inp) (bf16).
// A fp32 [M,K] lda, B fp32 [K,N] ldb=N. 64x64 tile, BK=16, 256 thr, 4x4 micro.
__global__ void __launch_bounds__(256)
sgemm_init_kernel(const float* __restrict__ A, int lda,
                  const float* __restrict__ B,
                  unsigned short* __restrict__ inp_bf,
                  unsigned short* __restrict__ msg_bf,
                  int M, int N, int K)
{
    __shared__ __align__(16) float Ast[16][68];
    __shared__ __align__(16) float Bs[16][64];

    const int tid = threadIdx.x;
    const int tx = tid & 15;
    const int ty = tid >> 4;
    const int n0 = blockIdx.x * 64;
    const int m0 = blockIdx.y * 64;

    float acc[4][4] = {};

    for (int k0 = 0; k0 < K; k0 += 16) {
#pragma unroll
        for (int l = 0; l < 4; ++l) {
            int q = tid + l * 256;
            int r = q >> 4, kk = q & 15;
            int m = m0 + r, k = k0 + kk;
            Ast[kk][r] = (m < M && k < K) ? A[(size_t)m * lda + k] : 0.0f;
        }
#pragma unroll
        for (int l = 0; l < 4; ++l) {
            int q = tid + l * 256;
            int kr = q >> 6, c = q & 63;
            int k = k0 + kr, n = n0 + c;
            Bs[kr][c] = (k < K && n < N) ? B[(size_t)k * N + n] : 0.0f;
        }
        __syncthreads();

#pragma unroll
        for (int kk = 0; kk < 16; ++kk) {
            float4 a4 = *(const float4*)&Ast[kk][ty * 4];
            float4 b4 = *(const float4*)&Bs[kk][tx * 4];
            float av[4] = {a4.x, a4.y, a4.z, a4.w};
            float bv[4] = {b4.x, b4.y, b4.z, b4.w};
#pragma unroll
            for (int r = 0; r < 4; ++r)
#pragma unroll
                for (int c = 0; c < 4; ++c)
                    acc[r][c] += av[r] * bv[c];
        }
        __syncthreads();
    }

#pragma unroll
    for (int r = 0; r < 4; ++r) {
        int m = m0 + ty * 4 + r;
        if (m >= M) continue;
#pragma unroll
        for (int c = 0; c < 4; ++c) {
            int n = n0 + tx * 4 + c;
            if (n >= N) continue;
            size_t idx = (size_t)m * N + n;
            float v = acc[r][c];
            inp_bf[idx] = f2bf(v);
            msg_bf[idx] = f2bf(fmaxf(v, 0.0f));
        }
    }
}

// ---------------------------------------------------------------------------
// Message-passing GEMM (fused bond update):
// msg_out = relu(inp + (amsg[b2a[m]] - msg_in[b2revb[m]]) @ W_h)
// A is built on the fly from bf16 gathers; B (W_h) fp32 [300,300].
__global__ void __launch_bounds__(256)
sgemm_mp_kernel(const unsigned short* __restrict__ amsg_bf,
                const unsigned short* __restrict__ msg_in_bf,
                const int* __restrict__ b2a,
                const int* __restrict__ b2revb,
                const float* __restrict__ B,
                const unsigned short* __restrict__ inp_bf,
                unsigned short* __restrict__ msg_out_bf,
                int M, int N, int K)
{
    __shared__ __align__(16) float Ast[16][68];
    __shared__ __align__(16) float Bs[16][64];

    const int tid = threadIdx.x;
    const int tx = tid & 15;
    const int ty = tid >> 4;
    const int n0 = blockIdx.x * 64;
    const int m0 = blockIdx.y * 64;

    float acc[4][4] = {};

    for (int k0 = 0; k0 < K; k0 += 16) {
#pragma unroll
        for (int l = 0; l < 4; ++l) {
            int q = tid + l * 256;
            int r = q >> 4, kk = q & 15;
            int m = m0 + r, k = k0 + kk;
            float v = 0.0f;
            if (m < M && k < K) {
                int ba = b2a[m];
                int br = b2revb[m];
                v = bf2f(amsg_bf[(size_t)ba * H + k]) -
                    bf2f(msg_in_bf[(size_t)br * H + k]);
            }
            Ast[kk][r] = v;
        }
#pragma unroll
        for (int l = 0; l < 4; ++l) {
            int q = tid + l * 256;
            int kr = q >> 6, c = q & 63;
            int k = k0 + kr, n = n0 + c;
            Bs[kr][c] = (k < K && n < N) ? B[(size_t)k * N + n] : 0.0f;
        }
        __syncthreads();

#pragma unroll
        for (int kk = 0; kk < 16; ++kk) {
            float4 a4 = *(const float4*)&Ast[kk][ty * 4];
            float4 b4 = *(const float4*)&Bs[kk][tx * 4];
            float av[4] = {a4.x, a4.y, a4.z, a4.w};
            float bv[4] = {b4.x, b4.y, b4.z, b4.w};
#pragma unroll
            for (int r = 0; r < 4; ++r)
#pragma unroll
                for (int c = 0; c < 4; ++c)
                    acc[r][c] += av[r] * bv[c];
        }
        __syncthreads();
    }

#pragma unroll
    for (int r = 0; r < 4; ++r) {
        int m = m0 + ty * 4 + r;
        if (m >= M) continue;
#pragma unroll
        for (int c = 0; c < 4; ++c) {
            int n = n0 + tx * 4 + c;
            if (n >= N) continue;
            size_t idx = (size_t)m * N + n;
            float v = acc[r][c] + bf2f(inp_bf[idx]);
            msg_out_bf[idx] = f2bf(fmaxf(v, 0.0f));
        }
    }
}

// ---------------------------------------------------------------------------
// Final GEMM over virtual concat A = [f_atoms (fp32, K1) | amsg (bf16, K2)],
// + bias + relu -> atom_hiddens fp32.
__global__ void __launch_bounds__(256)
sgemm_cat_kernel(const float* __restrict__ A1, int K1,
                 const unsigned short* __restrict__ A2_bf, int K2,
                 const float* __restrict__ B,
                 const float* __restrict__ bias,
                 float* __restrict__ Cact,
                 int M, int N)
{
    __shared__ __align__(16) float Ast[16][68];
    __shared__ __align__(16) float Bs[16][64];

    const int K = K1 + K2;
    const int tid = threadIdx.x;
    const int tx = tid & 15;
    const int ty = tid >> 4;
    const int n0 = blockIdx.x * 64;
    const int m0 = blockIdx.y * 64;

    float acc[4][4] = {};

    for (int k0 = 0; k0 < K; k0 += 16) {
#pragma unroll
        for (int l = 0; l < 4; ++l) {
            int q = tid + l * 256;
            int r = q >> 4, kk = q & 15;
            int m = m0 + r, k = k0 + kk;
            float v = 0.0f;
            if (m < M && k < K)
                v = (k < K1) ? A1[(size_t)m * K1 + k]
                             : bf2f(A2_bf[(size_t)m * K2 + (k - K1)]);
            Ast[kk][r] = v;
        }
#pragma unroll
        for (int l = 0; l < 4; ++l) {
            int q = tid + l * 256;
            int kr = q >> 6, c = q & 63;
            int k = k0 + kr, n = n0 + c;
            Bs[kr][c] = (k < K && n < N) ? B[(size_t)k * N + n] : 0.0f;
        }
        __syncthreads();

#pragma unroll
        for (int kk = 0; kk < 16; ++kk) {
            float4 a4 = *(const float4*)&Ast[kk][ty * 4];
            float4 b4 = *(const float4*)&Bs[kk][tx * 4];
            float av[4] = {a4.x, a4.y, a4.z, a4.w};
            float bv[4] = {b4.x, b4.y, b4.z, b4.w};
#pragma unroll
            for (int r = 0; r < 4; ++r)
#pragma unroll
                for (int c = 0; c < 4; ++c)
                    acc[r][c] += av[r] * bv[c];
        }
        __syncthreads();
    }

#pragma unroll
    for (int r = 0; r < 4; ++r) {
        int m = m0 + ty * 4 + r;
        if (m >= M) continue;
#pragma unroll
        for (int c = 0; c < 4; ++c) {
            int n = n0 + tx * 4 + c;
            if (n >= N) continue;
            float v = acc[r][c] + bias[n];
            Cact[(size_t)m * N + n] = fmaxf(v, 0.0f);
        }
    }
}

// ---------------------------------------------------------------------------
// amsg[i,:] = sum_{j<6} msg[a2b[i][j], :]   (bf16 in/out, fp32 accumulate)
// One thread per 4 contiguous bf16 (8 bytes).
__global__ void aggregate_kernel(const unsigned short* __restrict__ msg_bf,
                                 const int* __restrict__ a2b,
                                 unsigned short* __restrict__ amsg_bf,
                                 int n_atoms)
{
    int gid = blockIdx.x * blockDim.x + threadIdx.x;
    int total = n_atoms * H4;   // H4 groups of 4 bf16
    if (gid >= total) return;
    int atom = gid / H4;
    int c4 = gid - atom * H4;   // group index
    const int* nb = a2b + atom * MAXNB;
    float a0 = 0.f, a1 = 0.f, a2 = 0.f, a3 = 0.f;
#pragma unroll
    for (int j = 0; j < MAXNB; ++j) {
        int b = nb[j];
        uint2 v = *(const uint2*)(msg_bf + (size_t)b * H + c4 * 4);
        a0 += bf2f((unsigned short)(v.x & 0xFFFFu));
        a1 += bf2f((unsigned short)(v.x >> 16));
        a2 += bf2f((unsigned short)(v.y & 0xFFFFu));
        a3 += bf2f((unsigned short)(v.y >> 16));
    }
    uint2 o;
    o.x = (unsigned int)f2bf(a0) | ((unsigned int)f2bf(a1) << 16);
    o.y = (unsigned int)f2bf(a2) | ((unsigned int)f2bf(a3) << 16);
    *(uint2*)(amsg_bf + (size_t)atom * H + c4 * 4) = o;
}

// ---------------------------------------------------------------------------
// Per-molecule mean over sorted mol_id via binary search. One block per mol.
__global__ void __launch_bounds__(128)
segmean_kernel(const float* __restrict__ ah,
               const int* __restrict__ mol_id,
               int n_atoms,
               float* __restrict__ out)
{
    int m = blockIdx.x;
    int lo = 0, hi = n_atoms;
    while (lo < hi) { int mid = (lo + hi) >> 1; if (mol_id[mid] < m) lo = mid + 1; else hi = mid; }
    int start = lo;
    hi = n_atoms;
    while (lo < hi) { int mid = (lo + hi) >> 1; if (mol_id[mid] < m + 1) lo = mid + 1; else hi = mid; }
    int end = lo;

    int c = threadIdx.x;
    float a0 = 0.f, a1 = 0.f, a2 = 0.f;
    for (int a = start; a < end; ++a) {
        const float* row = ah + (size_t)a * H;
        a0 += row[c];
        a1 += row[c + 128];
        if (c < H - 256) a2 += row[c + 256];
    }
    float inv = (end > start) ? 1.0f / (float)(end - start) : 0.0f;
    float* orow = out + (size_t)m * H;
    orow[c] = a0 * inv;
    orow[c + 128] = a1 * inv;
    if (c < H - 256) orow[c + 256] = a2 * inv;
}

// ---------------------------------------------------------------------------
extern "C" void kernel_launch(void* const* d_in, const int* in_sizes, int n_in,
                              void* d_out, int out_size, void* d_ws, size_t ws_size,
                              hipStream_t stream)
{
    const float* f_atoms = (const float*)d_in[0];
    const float* f_bonds = (const float*)d_in[1];
    const int*   a2b     = (const int*)d_in[2];
    const int*   b2a     = (const int*)d_in[3];
    const int*   b2revb  = (const int*)d_in[4];
    const int*   mol_id  = (const int*)d_in[5];
    const float* W_i     = (const float*)d_in[7];
    const float* W_h     = (const float*)d_in[8];
    const float* W_o     = (const float*)d_in[9];
    const float* b_o     = (const float*)d_in[10];

    const int n_atoms   = in_sizes[5];
    const int n_bonds   = in_sizes[3];
    const int atom_fdim = in_sizes[0] / n_atoms;   // 133
    const int bond_fdim = in_sizes[1] / n_bonds;   // 147
    const int n_mols    = out_size / H;            // 2000

    // Workspace (bf16 shorts): inp | msgA | msgB | amsg   -> 210 MB total
    // atom_hiddens (fp32) overlays msgB at the end (msgB free after iter 2).
    size_t bondsH = (size_t)n_bonds * H;
    unsigned short* inp  = (unsigned short*)d_ws;
    unsigned short* msgA = inp + bondsH;
    unsigned short* msgB = msgA + bondsH;
    unsigned short* amsg = msgB + bondsH;
    float* ah = (float*)msgB;

    dim3 blk(256);
    dim3 gB((H + 63) / 64, (n_bonds + 63) / 64);
    dim3 gA((H + 63) / 64, (n_atoms + 63) / 64);
    const int aggBlocks = (n_atoms * H4 + 255) / 256;

    // inp = f_bonds @ W_i ; msgA = relu(inp)
    sgemm_init_kernel<<<gB, blk, 0, stream>>>(f_bonds, bond_fdim, W_i,
                                              inp, msgA, n_bonds, H, bond_fdim);

    // iter 1: msgA -> msgB
    aggregate_kernel<<<aggBlocks, blk, 0, stream>>>(msgA, a2b, amsg, n_atoms);
    sgemm_mp_kernel<<<gB, blk, 0, stream>>>(amsg, msgA, b2a, b2revb, W_h,
                                            inp, msgB, n_bonds, H, H);

    // iter 2: msgB -> msgA
    aggregate_kernel<<<aggBlocks, blk, 0, stream>>>(msgB, a2b, amsg, n_atoms);
    sgemm_mp_kernel<<<gB, blk, 0, stream>>>(amsg, msgB, b2a, b2revb, W_h,
                                            inp, msgA, n_bonds, H, H);

    // final aggregation from msgA
    aggregate_kernel<<<aggBlocks, blk, 0, stream>>>(msgA, a2b, amsg, n_atoms);

    // atom_hiddens = relu([f_atoms | amsg] @ W_o + b_o)  (fp32, overlays msgB)
    sgemm_cat_kernel<<<gA, blk, 0, stream>>>(f_atoms, atom_fdim, amsg, H,
                                             W_o, b_o, ah, n_atoms, H);

    // per-molecule mean
    segmean_kernel<<<n_mols, dim3(128), 0, stream>>>(ah, mol_id, n_atoms, (float*)d_out);
}

// Round 4
// 955.092 us; speedup vs baseline: 2.2042x; 2.2042x over previous
//
#include <hip/hip_runtime.h>
#include <cstddef>

#define H 300
#define MAXNB 6

typedef __attribute__((ext_vector_type(8)))  short bf16x8;
typedef __attribute__((ext_vector_type(16))) float f32x16;

__device__ __forceinline__ float bf2f(unsigned short u) {
    return __uint_as_float(((unsigned int)u) << 16);
}
__device__ __forceinline__ unsigned short f2bf(float f) {
    unsigned int u = __float_as_uint(f);
    u += 0x7FFFu + ((u >> 16) & 1u);
    return (unsigned short)(u >> 16);
}

// ---------------------------------------------------------------------------
// Wt[n][k] = bf16(W[k][n]), n<320 (pad 0), k<KPAD (pad 0). W is [K][N] fp32.
__global__ void __launch_bounds__(256)
wtrans_kernel(const float* __restrict__ W, unsigned short* __restrict__ Wt,
              int K, int N, int KPAD)
{
    int g = blockIdx.x * 256 + threadIdx.x;
    int total = 320 * KPAD;
    if (g >= total) return;
    int n = g / KPAD, k = g - n * KPAD;
    float v = (k < K && n < N) ? W[(size_t)k * N + n] : 0.0f;
    Wt[g] = f2bf(v);
}

// ---------------------------------------------------------------------------
// MFMA GEMM, C[M x 300] = act(A[M x K] @ W[K x 300]) variants.
// MODE 0 (init): A = f_bonds fp32 (lda=K1). out: inp_bf=raw, msg_bf=relu.
// MODE 1 (mp):   A = amsg[b2a[m]] - msg[b2revb[m]] (bf16 gathers).
//                out: msg_out = relu(inp + A@W).
// MODE 2 (cat):  A = [f_atoms fp32 (K1 cols) | amsg bf16 (300 cols)].
//                out fp32: ah = relu(A@W + bias).
// B given as Wt[n][k] bf16, n-padded to 320, k-padded to KPAD.
// Block: 256 thr = 4 waves (2M x 2N). Block tile 64 x 320. Wave tile 32 x 160.
template<int KPAD, int MODE>
__global__ void __launch_bounds__(256)
mfma_gemm(const void* __restrict__ Asrc1,
          const void* __restrict__ Asrc2,
          const int* __restrict__ b2a,
          const int* __restrict__ b2revb,
          const unsigned short* __restrict__ Wt,
          const unsigned short* __restrict__ inp_bf,
          const float* __restrict__ bias,
          unsigned short* __restrict__ out_bf1,
          unsigned short* __restrict__ out_bf2,
          float* __restrict__ out_f32,
          int M, int K1)
{
    constexpr int SA = KPAD + 8;           // halfs; stride pad to soften banks
    constexpr int G  = KPAD / 4;           // 4-half groups per row
    __shared__ unsigned short Ast[64 * SA];
    __shared__ int sidx[64], ridx[64];

    const int m0 = blockIdx.x * 64;

    if (MODE == 1) {
        if (threadIdx.x < 64) {
            int m = m0 + threadIdx.x;
            sidx[threadIdx.x] = (m < M) ? b2a[m] : 0;
            ridx[threadIdx.x] = (m < M) ? b2revb[m] : 0;
        }
        __syncthreads();
    }

    // ---- Stage A tile (64 x KPAD bf16) into LDS, gathered/converted/fused.
    for (int g = threadIdx.x; g < 64 * G; g += 256) {
        int r = g / G;
        int k = (g - r * G) * 4;
        int m = m0 + r;
        uint2 o = make_uint2(0u, 0u);
        if (MODE == 1) {
            if (k < H) {
                const unsigned short* pa = (const unsigned short*)Asrc1 + (size_t)sidx[r] * H + k;
                const unsigned short* pm = (const unsigned short*)Asrc2 + (size_t)ridx[r] * H + k;
                uint2 va = *(const uint2*)pa;
                uint2 vm = *(const uint2*)pm;
                float d0 = bf2f((unsigned short)(va.x & 0xFFFFu)) - bf2f((unsigned short)(vm.x & 0xFFFFu));
                float d1 = bf2f((unsigned short)(va.x >> 16))     - bf2f((unsigned short)(vm.x >> 16));
                float d2 = bf2f((unsigned short)(va.y & 0xFFFFu)) - bf2f((unsigned short)(vm.y & 0xFFFFu));
                float d3 = bf2f((unsigned short)(va.y >> 16))     - bf2f((unsigned short)(vm.y >> 16));
                o.x = (unsigned int)f2bf(d0) | ((unsigned int)f2bf(d1) << 16);
                o.y = (unsigned int)f2bf(d2) | ((unsigned int)f2bf(d3) << 16);
            }
        } else if (MODE == 0) {
            if (m < M) {
                unsigned short h[4];
#pragma unroll
                for (int i = 0; i < 4; ++i) {
                    int kk = k + i;
                    h[i] = (kk < K1) ? f2bf(((const float*)Asrc1)[(size_t)m * K1 + kk]) : (unsigned short)0;
                }
                o.x = (unsigned int)h[0] | ((unsigned int)h[1] << 16);
                o.y = (unsigned int)h[2] | ((unsigned int)h[3] << 16);
            }
        } else { // MODE 2: [f_atoms fp32 K1 | amsg bf16 H]
            if (m < M) {
                unsigned short h[4];
#pragma unroll
                for (int i = 0; i < 4; ++i) {
                    int kk = k + i;
                    unsigned short hv = 0;
                    if (kk < K1)
                        hv = f2bf(((const float*)Asrc1)[(size_t)m * K1 + kk]);
                    else if (kk < K1 + H)
                        hv = ((const unsigned short*)Asrc2)[(size_t)m * H + (kk - K1)];
                    h[i] = hv;
                }
                o.x = (unsigned int)h[0] | ((unsigned int)h[1] << 16);
                o.y = (unsigned int)h[2] | ((unsigned int)h[3] << 16);
            }
        }
        *(uint2*)&Ast[r * SA + k] = o;
    }
    __syncthreads();

    // ---- MFMA main loop (no barriers; B streamed from global/L2).
    const int lane  = threadIdx.x & 63;
    const int w     = threadIdx.x >> 6;
    const int rbase = (w >> 1) * 32;     // wave row base in block tile
    const int cbase = (w & 1) * 160;     // wave col base
    const int mrow  = lane & 31;
    const int quad  = lane >> 5;

    f32x16 acc[5];
#pragma unroll
    for (int t = 0; t < 5; ++t)
#pragma unroll
        for (int i = 0; i < 16; ++i) acc[t][i] = 0.0f;

#pragma unroll 2
    for (int s = 0; s < KPAD / 16; ++s) {
        int k0 = s * 16;
        bf16x8 a = *(const bf16x8*)&Ast[(rbase + mrow) * SA + k0 + quad * 8];
#pragma unroll
        for (int nt = 0; nt < 5; ++nt) {
            int n = cbase + nt * 32 + mrow;
            bf16x8 b = *(const bf16x8*)&Wt[(size_t)n * KPAD + k0 + quad * 8];
            acc[nt] = __builtin_amdgcn_mfma_f32_32x32x16_bf16(a, b, acc[nt], 0, 0, 0);
        }
    }

    // ---- Epilogue. C/D: col = lane&31, row = (reg&3) + 8*(reg>>2) + 4*quad.
#pragma unroll
    for (int nt = 0; nt < 5; ++nt) {
        int col = cbase + nt * 32 + mrow;
        if (col >= H) continue;
#pragma unroll
        for (int r = 0; r < 16; ++r) {
            int row = m0 + rbase + (r & 3) + 8 * (r >> 2) + 4 * quad;
            if (row >= M) continue;
            size_t idx = (size_t)row * H + col;
            float v = acc[nt][r];
            if (MODE == 0) {
                out_bf1[idx] = f2bf(v);
                out_bf2[idx] = f2bf(fmaxf(v, 0.0f));
            } else if (MODE == 1) {
                v += bf2f(inp_bf[idx]);
                out_bf1[idx] = f2bf(fmaxf(v, 0.0f));
            } else {
                v += bias[col];
                out_f32[idx] = fmaxf(v, 0.0f);
            }
        }
    }
}

// ---------------------------------------------------------------------------
// amsg[i,:] = sum_{j<6} msg[a2b[i][j], :]   (bf16 in/out, fp32 accumulate)
__global__ void aggregate_kernel(const unsigned short* __restrict__ msg_bf,
                                 const int* __restrict__ a2b,
                                 unsigned short* __restrict__ amsg_bf,
                                 int n_atoms)
{
    int gid = blockIdx.x * blockDim.x + threadIdx.x;
    int total = n_atoms * (H / 4);
    if (gid >= total) return;
    int atom = gid / (H / 4);
    int c4 = gid - atom * (H / 4);
    const int* nb = a2b + atom * MAXNB;
    float a0 = 0.f, a1 = 0.f, a2 = 0.f, a3 = 0.f;
#pragma unroll
    for (int j = 0; j < MAXNB; ++j) {
        int b = nb[j];
        uint2 v = *(const uint2*)(msg_bf + (size_t)b * H + c4 * 4);
        a0 += bf2f((unsigned short)(v.x & 0xFFFFu));
        a1 += bf2f((unsigned short)(v.x >> 16));
        a2 += bf2f((unsigned short)(v.y & 0xFFFFu));
        a3 += bf2f((unsigned short)(v.y >> 16));
    }
    uint2 o;
    o.x = (unsigned int)f2bf(a0) | ((unsigned int)f2bf(a1) << 16);
    o.y = (unsigned int)f2bf(a2) | ((unsigned int)f2bf(a3) << 16);
    *(uint2*)(amsg_bf + (size_t)atom * H + c4 * 4) = o;
}

// ---------------------------------------------------------------------------
// Per-molecule mean over sorted mol_id via binary search. One block per mol.
__global__ void __launch_bounds__(128)
segmean_kernel(const float* __restrict__ ah,
               const int* __restrict__ mol_id,
               int n_atoms,
               float* __restrict__ out)
{
    int m = blockIdx.x;
    int lo = 0, hi = n_atoms;
    while (lo < hi) { int mid = (lo + hi) >> 1; if (mol_id[mid] < m) lo = mid + 1; else hi = mid; }
    int start = lo;
    hi = n_atoms;
    while (lo < hi) { int mid = (lo + hi) >> 1; if (mol_id[mid] < m + 1) lo = mid + 1; else hi = mid; }
    int end = lo;

    int c = threadIdx.x;
    float a0 = 0.f, a1 = 0.f, a2 = 0.f;
    for (int a = start; a < end; ++a) {
        const float* row = ah + (size_t)a * H;
        a0 += row[c];
        a1 += row[c + 128];
        if (c < H - 256) a2 += row[c + 256];
    }
    float inv = (end > start) ? 1.0f / (float)(end - start) : 0.0f;
    float* orow = out + (size_t)m * H;
    orow[c] = a0 * inv;
    orow[c + 128] = a1 * inv;
    if (c < H - 256) orow[c + 256] = a2 * inv;
}

// ---------------------------------------------------------------------------
extern "C" void kernel_launch(void* const* d_in, const int* in_sizes, int n_in,
                              void* d_out, int out_size, void* d_ws, size_t ws_size,
                              hipStream_t stream)
{
    const float* f_atoms = (const float*)d_in[0];
    const float* f_bonds = (const float*)d_in[1];
    const int*   a2b     = (const int*)d_in[2];
    const int*   b2a     = (const int*)d_in[3];
    const int*   b2revb  = (const int*)d_in[4];
    const int*   mol_id  = (const int*)d_in[5];
    const float* W_i     = (const float*)d_in[7];
    const float* W_h     = (const float*)d_in[8];
    const float* W_o     = (const float*)d_in[9];
    const float* b_o     = (const float*)d_in[10];

    const int n_atoms   = in_sizes[5];
    const int n_bonds   = in_sizes[3];
    const int atom_fdim = in_sizes[0] / n_atoms;   // 133
    const int bond_fdim = in_sizes[1] / n_bonds;   // 147
    const int n_mols    = out_size / H;            // 2000

    // KPADs: init=160 (K=147), mp=320 (K=300), cat=448 (K=433)
    size_t bondsH = (size_t)n_bonds * H;
    size_t atomsH = (size_t)n_atoms * H;
    unsigned short* inp  = (unsigned short*)d_ws;
    unsigned short* msgA = inp + bondsH;
    unsigned short* msgB = msgA + bondsH;
    unsigned short* amsg = msgB + bondsH;
    unsigned short* Wt_i = amsg + atomsH;
    unsigned short* Wt_h = Wt_i + 320 * 160;
    unsigned short* Wt_o = Wt_h + 320 * 320;
    float* ah = (float*)msgB;   // fp32 atom_hiddens overlays msgB (same 60 MB)

    dim3 blk(256);

    // Pre-transpose weights to bf16 Wt[n][k]
    wtrans_kernel<<<(320 * 160 + 255) / 256, blk, 0, stream>>>(W_i, Wt_i, bond_fdim, H, 160);
    wtrans_kernel<<<(320 * 320 + 255) / 256, blk, 0, stream>>>(W_h, Wt_h, H, H, 320);
    wtrans_kernel<<<(320 * 448 + 255) / 256, blk, 0, stream>>>(W_o, Wt_o, atom_fdim + H, H, 448);

    const int gBonds = (n_bonds + 63) / 64;
    const int gAtoms = (n_atoms + 63) / 64;
    const int aggBlocks = (n_atoms * (H / 4) + 255) / 256;

    // inp = f_bonds @ W_i ; msgA = relu(inp)
    mfma_gemm<160, 0><<<gBonds, blk, 0, stream>>>(
        f_bonds, nullptr, nullptr, nullptr, Wt_i, nullptr, nullptr,
        inp, msgA, nullptr, n_bonds, bond_fdim);

    // iter 1: msgA -> msgB
    aggregate_kernel<<<aggBlocks, blk, 0, stream>>>(msgA, a2b, amsg, n_atoms);
    mfma_gemm<320, 1><<<gBonds, blk, 0, stream>>>(
        amsg, msgA, b2a, b2revb, Wt_h, inp, nullptr,
        msgB, nullptr, nullptr, n_bonds, H);

    // iter 2: msgB -> msgA
    aggregate_kernel<<<aggBlocks, blk, 0, stream>>>(msgB, a2b, amsg, n_atoms);
    mfma_gemm<320, 1><<<gBonds, blk, 0, stream>>>(
        amsg, msgB, b2a, b2revb, Wt_h, inp, nullptr,
        msgA, nullptr, nullptr, n_bonds, H);

    // final aggregation from msgA
    aggregate_kernel<<<aggBlocks, blk, 0, stream>>>(msgA, a2b, amsg, n_atoms);

    // atom_hiddens = relu([f_atoms | amsg] @ W_o + b_o)  (fp32, overlays msgB)
    mfma_gemm<448, 2><<<gAtoms, blk, 0, stream>>>(
        f_atoms, amsg, nullptr, nullptr, Wt_o, nullptr, b_o,
        nullptr, nullptr, ah, n_atoms, atom_fdim);

    // per-molecule mean
    segmean_kernel<<<n_mols, dim3(128), 0, stream>>>(ah, mol_id, n_atoms, (float*)d_out);
}

// Round 6
// 730.060 us; speedup vs baseline: 2.8836x; 1.3082x over previous
//
#include <hip/hip_runtime.h>
#include <cstddef>

#define H 300
#define RS 304            // row stride (halfs) for row-major bf16 buffers (16B-aligned rows)
#define MAXNB 6

typedef __attribute__((ext_vector_type(8)))  short bf16x8;
typedef __attribute__((ext_vector_type(16))) float f32x16;

__device__ __forceinline__ float bf2f(unsigned short u) {
    return __uint_as_float(((unsigned int)u) << 16);
}
__device__ __forceinline__ unsigned short f2bf(float f) {
    unsigned int u = __float_as_uint(f);
    u += 0x7FFFu + ((u >> 16) & 1u);
    return (unsigned short)(u >> 16);
}
__device__ __forceinline__ unsigned int sub2bf(unsigned int a, unsigned int b) {
    float d0 = bf2f((unsigned short)(a & 0xFFFFu)) - bf2f((unsigned short)(b & 0xFFFFu));
    float d1 = bf2f((unsigned short)(a >> 16))     - bf2f((unsigned short)(b >> 16));
    return (unsigned int)f2bf(d0) | ((unsigned int)f2bf(d1) << 16);
}

// ---------------------------------------------------------------------------
// Fragment packing convention (verified layout, Round-4 passed with it):
//   element (m, k) of A lives at buf[((m_blk*S + s)*64 + lane)*8 + j]
//   with m = m_blk*32 + (lane&31), k = s*16 + (lane>>5)*8 + j.
// Same for B with n in place of m.

// Pack fp32 dense [M x K] row-major into A-fragment bf16 layout (MB m_blks, S steps).
__global__ void __launch_bounds__(256)
pack_a_f32(const float* __restrict__ src, unsigned short* __restrict__ dst,
           int M, int K, int S, int MB)
{
    int g = blockIdx.x * 256 + threadIdx.x;
    int total = MB * S * 32;
    if (g >= total) return;
    int mrow = g & 31;
    int t = g >> 5;
    int s = t % S;
    int m_blk = t / S;
    int m = m_blk * 32 + mrow;
    unsigned int w[8];
#pragma unroll
    for (int q = 0; q < 2; ++q) {
#pragma unroll
        for (int p = 0; p < 4; ++p) {
            int k = s * 16 + q * 8 + p * 2;
            unsigned short h0 = (m < M && k     < K) ? f2bf(src[(size_t)m * K + k])     : (unsigned short)0;
            unsigned short h1 = (m < M && k + 1 < K) ? f2bf(src[(size_t)m * K + k + 1]) : (unsigned short)0;
            w[q * 4 + p] = (unsigned int)h0 | ((unsigned int)h1 << 16);
        }
    }
    size_t base = ((size_t)(m_blk * S + s) * 64) * 8;
    uint4 o0 = make_uint4(w[0], w[1], w[2], w[3]);
    uint4 o1 = make_uint4(w[4], w[5], w[6], w[7]);
    *(uint4*)&dst[base + (size_t)(0 * 32 + mrow) * 8] = o0;
    *(uint4*)&dst[base + (size_t)(1 * 32 + mrow) * 8] = o1;
}

// Pack stacked weights [src1 (K1 valid rows, S1 steps) ; src2 (K2 valid rows)] into
// B-fragment layout, N=300 padded to 320, SB total steps. src fp32 [*][300].
__global__ void __launch_bounds__(256)
pack_b(const float* __restrict__ src1, const float* __restrict__ src2,
       unsigned short* __restrict__ dst, int K1, int S1, int K2, int SB)
{
    int g = blockIdx.x * 256 + threadIdx.x;
    if (g >= 10 * SB * 64) return;
    int lane = g & 63;
    int t = g >> 6;
    int s = t % SB;
    int n_blk = t / SB;
    int n = n_blk * 32 + (lane & 31);
    unsigned int w[4];
#pragma unroll
    for (int p = 0; p < 4; ++p) {
        unsigned short h[2];
#pragma unroll
        for (int e = 0; e < 2; ++e) {
            int kf = s * 16 + (lane >> 5) * 8 + p * 2 + e;
            float v = 0.0f;
            if (n < H) {
                if (s < S1) {
                    if (kf < K1) v = src1[(size_t)kf * H + n];
                } else {
                    int k2 = kf - S1 * 16;
                    if (k2 < K2) v = src2[(size_t)k2 * H + n];
                }
            }
            h[e] = f2bf(v);
        }
        w[p] = (unsigned int)h[0] | ((unsigned int)h[1] << 16);
    }
    *(uint4*)&dst[(size_t)g * 8] = make_uint4(w[0], w[1], w[2], w[3]);
}

// ---------------------------------------------------------------------------
// Bond update -> packed A fragments: dmsg(m,k) = amsg[b2a[m]][k] - msg[b2revb[m]][k]
__global__ void __launch_bounds__(256)
bond_update_pack(const unsigned short* __restrict__ amsg,
                 const unsigned short* __restrict__ msg,
                 const int* __restrict__ b2a, const int* __restrict__ b2revb,
                 unsigned short* __restrict__ dmsg, int M, int MB)
{
    int g = blockIdx.x * 256 + threadIdx.x;
    int total = MB * 20 * 32;
    if (g >= total) return;
    int mrow = g & 31;
    int t = g >> 5;
    int s = t % 20;
    int m_blk = t / 20;
    int m = m_blk * 32 + mrow;
    bool valid = (m < M);
    int sa = valid ? b2a[m] : 0;
    int sr = valid ? b2revb[m] : 0;
    size_t base = ((size_t)(m_blk * 20 + s) * 64) * 8;
#pragma unroll
    for (int q = 0; q < 2; ++q) {
        int k = s * 16 + q * 8;
        uint4 o = make_uint4(0u, 0u, 0u, 0u);
        if (valid && k < RS) {
            uint4 va = *(const uint4*)&amsg[(size_t)sa * RS + k];
            uint4 vm = *(const uint4*)&msg[(size_t)sr * RS + k];
            o.x = sub2bf(va.x, vm.x);
            o.y = sub2bf(va.y, vm.y);
            o.z = sub2bf(va.z, vm.z);
            o.w = sub2bf(va.w, vm.w);
        }
        *(uint4*)&dmsg[base + (size_t)(q * 32 + mrow) * 8] = o;
    }
}

// ---------------------------------------------------------------------------
// Row-major aggregate: amsg[a][:] = sum_j msg[a2b[a][j]][:]; pads [300,304) zeroed.
__global__ void __launch_bounds__(256)
aggregate_row(const unsigned short* __restrict__ msg, const int* __restrict__ a2b,
              unsigned short* __restrict__ amsg, int n_atoms)
{
    int gid = blockIdx.x * 256 + threadIdx.x;
    int total = n_atoms * 76;
    if (gid >= total) return;
    int atom = gid / 76;
    int gcol = gid - atom * 76;
    if (gcol == 75) {
        *(uint2*)&amsg[(size_t)atom * RS + 300] = make_uint2(0u, 0u);
        return;
    }
    const int* nb = a2b + atom * MAXNB;
    float a0 = 0.f, a1 = 0.f, a2 = 0.f, a3 = 0.f;
#pragma unroll
    for (int j = 0; j < MAXNB; ++j) {
        int b = nb[j];
        uint2 v = *(const uint2*)&msg[(size_t)b * RS + gcol * 4];
        a0 += bf2f((unsigned short)(v.x & 0xFFFFu));
        a1 += bf2f((unsigned short)(v.x >> 16));
        a2 += bf2f((unsigned short)(v.y & 0xFFFFu));
        a3 += bf2f((unsigned short)(v.y >> 16));
    }
    uint2 o;
    o.x = (unsigned int)f2bf(a0) | ((unsigned int)f2bf(a1) << 16);
    o.y = (unsigned int)f2bf(a2) | ((unsigned int)f2bf(a3) << 16);
    *(uint2*)&amsg[(size_t)atom * RS + gcol * 4] = o;
}

// Aggregate directly into packed A fragments (for the final cat GEMM), S=20.
__global__ void __launch_bounds__(256)
aggregate_pack(const unsigned short* __restrict__ msg, const int* __restrict__ a2b,
               unsigned short* __restrict__ apack, int n_atoms, int MB)
{
    int g = blockIdx.x * 256 + threadIdx.x;
    int total = MB * 20 * 32;
    if (g >= total) return;
    int mrow = g & 31;
    int t = g >> 5;
    int s = t % 20;
    int m_blk = t / 20;
    int m = m_blk * 32 + mrow;
    size_t base = ((size_t)(m_blk * 20 + s) * 64) * 8;
#pragma unroll
    for (int q = 0; q < 2; ++q) {
        int k = s * 16 + q * 8;
        uint4 o = make_uint4(0u, 0u, 0u, 0u);
        if (m < n_atoms && k < RS) {
            const int* nb = a2b + m * MAXNB;
            float sum[8] = {};
#pragma unroll
            for (int j = 0; j < MAXNB; ++j) {
                int b = nb[j];
                uint4 v = *(const uint4*)&msg[(size_t)b * RS + k];
                unsigned int ww[4] = {v.x, v.y, v.z, v.w};
#pragma unroll
                for (int p = 0; p < 4; ++p) {
                    sum[p * 2]     += bf2f((unsigned short)(ww[p] & 0xFFFFu));
                    sum[p * 2 + 1] += bf2f((unsigned short)(ww[p] >> 16));
                }
            }
            unsigned int ow[4];
#pragma unroll
            for (int p = 0; p < 4; ++p)
                ow[p] = (unsigned int)f2bf(sum[p * 2]) | ((unsigned int)f2bf(sum[p * 2 + 1]) << 16);
            o = make_uint4(ow[0], ow[1], ow[2], ow[3]);
        }
        *(uint4*)&apack[base + (size_t)(q * 32 + mrow) * 8] = o;
    }
}

// ---------------------------------------------------------------------------
// Packed-fragment MFMA GEMM: out[m][0..300) = relu( [A1|A2] @ B + bias ), bf16 out,
// row stride RS. A1: S1 steps, A2: S2 steps, B: SB=S1+S2 steps (N padded to 320).
// Block 256 = 4 waves (2 m_blks x 2 col-halves). No LDS in K-loop; LDS C-transpose.
template<int S1, int S2, int SB>
__global__ void __launch_bounds__(256)
gemm_packed(const unsigned short* __restrict__ A1,
            const unsigned short* __restrict__ A2,
            const unsigned short* __restrict__ Bp,
            const float* __restrict__ bias,
            unsigned short* __restrict__ out, int M)
{
    __shared__ unsigned short Cs[64][308];

    const int lane  = threadIdx.x & 63;
    const int w     = threadIdx.x >> 6;
    const int rbase = (w >> 1) * 32;
    const int cbase = (w & 1) * 160;
    const int mrow  = lane & 31;
    const int quad  = lane >> 5;
    const int m0    = blockIdx.x * 64;
    const int m_blk = blockIdx.x * 2 + (w >> 1);

    f32x16 acc[5];
#pragma unroll
    for (int t = 0; t < 5; ++t)
#pragma unroll
        for (int i = 0; i < 16; ++i) acc[t][i] = 0.0f;

    // FIX (R5 bug): base index is ((m_blk*S + s)*64 + lane)*8 — the *8 applies
    // to the whole lane index, not just `lane`.
    const unsigned short* aptr = A1 + ((size_t)m_blk * S1 * 64 + (size_t)lane) * 8;
#pragma unroll 2
    for (int s = 0; s < S1; ++s) {
        bf16x8 a = *(const bf16x8*)(aptr + (size_t)s * 512);
#pragma unroll
        for (int nt = 0; nt < 5; ++nt) {
            int n_blk = (cbase >> 5) + nt;
            bf16x8 b = *(const bf16x8*)(Bp + ((size_t)(n_blk * SB + s) * 64 + lane) * 8);
            acc[nt] = __builtin_amdgcn_mfma_f32_32x32x16_bf16(a, b, acc[nt], 0, 0, 0);
        }
    }
    if (S2 > 0) {
        const unsigned short* aptr2 = A2 + ((size_t)m_blk * S2 * 64 + (size_t)lane) * 8;
#pragma unroll 2
        for (int s = 0; s < S2; ++s) {
            bf16x8 a = *(const bf16x8*)(aptr2 + (size_t)s * 512);
#pragma unroll
            for (int nt = 0; nt < 5; ++nt) {
                int n_blk = (cbase >> 5) + nt;
                bf16x8 b = *(const bf16x8*)(Bp + ((size_t)(n_blk * SB + S1 + s) * 64 + lane) * 8);
                acc[nt] = __builtin_amdgcn_mfma_f32_32x32x16_bf16(a, b, acc[nt], 0, 0, 0);
            }
        }
    }

    // C/D layout: col = lane&31 (+tile), row = (reg&3) + 8*(reg>>2) + 4*quad (+rbase)
#pragma unroll
    for (int nt = 0; nt < 5; ++nt) {
        int col = cbase + nt * 32 + mrow;
#pragma unroll
        for (int r = 0; r < 16; ++r) {
            int row = rbase + (r & 3) + 8 * (r >> 2) + 4 * quad;
            float v = acc[nt][r];
            if (bias && col < H) v += bias[col];
            if (col < 308) Cs[row][col] = f2bf(fmaxf(v, 0.0f));
        }
    }
    __syncthreads();

    for (int idx = threadIdx.x; idx < 64 * 76; idx += 256) {
        int row = idx / 76;
        int gcol = idx - row * 76;
        int m = m0 + row;
        if (m < M) {
            uint2 val = *(const uint2*)&Cs[row][gcol * 4];
            *(uint2*)&out[(size_t)m * RS + gcol * 4] = val;
        }
    }
}

// ---------------------------------------------------------------------------
// Per-molecule mean over sorted mol_id via binary search; ah is bf16 stride RS.
__global__ void __launch_bounds__(128)
segmean_kernel(const unsigned short* __restrict__ ah,
               const int* __restrict__ mol_id, int n_atoms,
               float* __restrict__ out)
{
    int m = blockIdx.x;
    int lo = 0, hi = n_atoms;
    while (lo < hi) { int mid = (lo + hi) >> 1; if (mol_id[mid] < m) lo = mid + 1; else hi = mid; }
    int start = lo;
    hi = n_atoms;
    while (lo < hi) { int mid = (lo + hi) >> 1; if (mol_id[mid] < m + 1) lo = mid + 1; else hi = mid; }
    int end = lo;

    int c = threadIdx.x;
    float a0 = 0.f, a1 = 0.f, a2 = 0.f;
    for (int a = start; a < end; ++a) {
        const unsigned short* row = ah + (size_t)a * RS;
        a0 += bf2f(row[c]);
        a1 += bf2f(row[c + 128]);
        if (c < H - 256) a2 += bf2f(row[c + 256]);
    }
    float inv = (end > start) ? 1.0f / (float)(end - start) : 0.0f;
    float* orow = out + (size_t)m * H;
    orow[c] = a0 * inv;
    orow[c + 128] = a1 * inv;
    if (c < H - 256) orow[c + 256] = a2 * inv;
}

// ---------------------------------------------------------------------------
extern "C" void kernel_launch(void* const* d_in, const int* in_sizes, int n_in,
                              void* d_out, int out_size, void* d_ws, size_t ws_size,
                              hipStream_t stream)
{
    const float* f_atoms = (const float*)d_in[0];
    const float* f_bonds = (const float*)d_in[1];
    const int*   a2b     = (const int*)d_in[2];
    const int*   b2a     = (const int*)d_in[3];
    const int*   b2revb  = (const int*)d_in[4];
    const int*   mol_id  = (const int*)d_in[5];
    const float* W_i     = (const float*)d_in[7];
    const float* W_h     = (const float*)d_in[8];
    const float* W_o     = (const float*)d_in[9];
    const float* b_o     = (const float*)d_in[10];

    const int n_atoms   = in_sizes[5];
    const int n_bonds   = in_sizes[3];
    const int atom_fdim = in_sizes[0] / n_atoms;   // 133
    const int bond_fdim = in_sizes[1] / n_bonds;   // 147
    const int n_mols    = out_size / H;            // 2000

    const int gBonds = (n_bonds + 63) / 64;        // 1563
    const int gAtoms = (n_atoms + 63) / 64;        // 782
    const int MBb = 2 * gBonds;                    // 3126 m_blks (bonds)
    const int MBa = 2 * gAtoms;                    // 1564 m_blks (atoms)

    // Workspace carve (halfs). Overlays: fap+apack reuse dmsg; ah reuses fbp.
    unsigned short* msg   = (unsigned short*)d_ws;                     // n_bonds*RS
    unsigned short* amsg  = msg  + (size_t)n_bonds * RS;               // n_atoms*RS
    unsigned short* fbp   = amsg + (size_t)n_atoms * RS;               // MBb*10*512
    unsigned short* dmsg  = fbp  + (size_t)MBb * 10 * 512;             // MBb*20*512
    unsigned short* wih   = dmsg + (size_t)MBb * 20 * 512;             // 10*30*512
    unsigned short* wo    = wih  + 10 * 30 * 512;                      // 10*29*512
    unsigned short* fap   = dmsg;                                      // MBa*9*512
    unsigned short* apack = dmsg + (size_t)MBa * 9 * 512;              // MBa*20*512
    unsigned short* ah    = fbp;                                       // n_atoms*RS

    dim3 blk(256);

    // Weight packs: Wih = [[W_i (147 rows, 10 steps)];[W_h (300 rows)]], SB=30
    pack_b<<<(10 * 30 * 64 + 255) / 256, blk, 0, stream>>>(W_i, W_h, wih, bond_fdim, 10, H, 30);
    // Wo = [[W_o rows 0..132 (9 steps)];[W_o rows 133..432]], SB=29
    pack_b<<<(10 * 29 * 64 + 255) / 256, blk, 0, stream>>>(W_o, W_o + (size_t)atom_fdim * H, wo,
                                                           atom_fdim, 9, H, 29);
    // Dense A packs
    pack_a_f32<<<(MBb * 10 * 32 + 255) / 256, blk, 0, stream>>>(f_bonds, fbp, n_bonds, bond_fdim, 10, MBb);

    // init: msg = relu(f_bonds @ W_i)
    gemm_packed<10, 0, 30><<<gBonds, blk, 0, stream>>>(fbp, nullptr, wih, nullptr, msg, n_bonds);

    const int aggRowBlocks  = (n_atoms * 76 + 255) / 256;
    const int bupBlocks     = (MBb * 20 * 32 + 255) / 256;
    const int aggPackBlocks = (MBa * 20 * 32 + 255) / 256;

    for (int it = 0; it < 2; ++it) {
        aggregate_row<<<aggRowBlocks, blk, 0, stream>>>(msg, a2b, amsg, n_atoms);
        bond_update_pack<<<bupBlocks, blk, 0, stream>>>(amsg, msg, b2a, b2revb, dmsg, n_bonds, MBb);
        // msg = relu([f_bonds | dmsg] @ [[W_i];[W_h]])  (in-place over msg)
        gemm_packed<10, 20, 30><<<gBonds, blk, 0, stream>>>(fbp, dmsg, wih, nullptr, msg, n_bonds);
    }

    // final aggregation -> packed fragments; f_atoms pack (overlays dmsg region)
    aggregate_pack<<<aggPackBlocks, blk, 0, stream>>>(msg, a2b, apack, n_atoms, MBa);
    pack_a_f32<<<(MBa * 9 * 32 + 255) / 256, blk, 0, stream>>>(f_atoms, fap, n_atoms, atom_fdim, 9, MBa);

    // ah = relu([f_atoms | amsg] @ W_o + b_o)   (bf16, overlays fbp)
    gemm_packed<9, 20, 29><<<gAtoms, blk, 0, stream>>>(fap, apack, wo, b_o, ah, n_atoms);

    // per-molecule mean
    segmean_kernel<<<n_mols, dim3(128), 0, stream>>>(ah, mol_id, n_atoms, (float*)d_out);
}

// Round 7
// 618.055 us; speedup vs baseline: 3.4061x; 1.1812x over previous
//
#include <hip/hip_runtime.h>
#include <cstddef>

#define H 300
#define RS 304            // row stride (halfs) for row-major bf16 buffers
#define MAXNB 6

typedef __attribute__((ext_vector_type(8)))  short bf16x8;
typedef __attribute__((ext_vector_type(16))) float f32x16;

__device__ __forceinline__ float bf2f(unsigned short u) {
    return __uint_as_float(((unsigned int)u) << 16);
}
__device__ __forceinline__ unsigned short f2bf(float f) {
    unsigned int u = __float_as_uint(f);
    u += 0x7FFFu + ((u >> 16) & 1u);
    return (unsigned short)(u >> 16);
}
__device__ __forceinline__ unsigned int sub2bf(unsigned int a, unsigned int b) {
    float d0 = bf2f((unsigned short)(a & 0xFFFFu)) - bf2f((unsigned short)(b & 0xFFFFu));
    float d1 = bf2f((unsigned short)(a >> 16))     - bf2f((unsigned short)(b >> 16));
    return (unsigned int)f2bf(d0) | ((unsigned int)f2bf(d1) << 16);
}
__device__ __forceinline__ bf16x8 subpack(uint4 a, uint4 b) {
    union { unsigned int u[4]; bf16x8 v; } r;
    r.u[0] = sub2bf(a.x, b.x);
    r.u[1] = sub2bf(a.y, b.y);
    r.u[2] = sub2bf(a.z, b.z);
    r.u[3] = sub2bf(a.w, b.w);
    return r.v;
}

// ---------------------------------------------------------------------------
// Fragment layout: element (m,k) at buf[((m_blk*S + s)*64 + lane)*8 + j],
// m = m_blk*32 + (lane&31), k = s*16 + (lane>>5)*8 + j. Same for B with n.

__global__ void __launch_bounds__(256)
pack_a_f32(const float* __restrict__ src, unsigned short* __restrict__ dst,
           int M, int K, int S, int MB)
{
    int g = blockIdx.x * 256 + threadIdx.x;
    int total = MB * S * 32;
    if (g >= total) return;
    int mrow = g & 31;
    int t = g >> 5;
    int s = t % S;
    int m_blk = t / S;
    int m = m_blk * 32 + mrow;
    unsigned int w[8];
#pragma unroll
    for (int q = 0; q < 2; ++q) {
#pragma unroll
        for (int p = 0; p < 4; ++p) {
            int k = s * 16 + q * 8 + p * 2;
            unsigned short h0 = (m < M && k     < K) ? f2bf(src[(size_t)m * K + k])     : (unsigned short)0;
            unsigned short h1 = (m < M && k + 1 < K) ? f2bf(src[(size_t)m * K + k + 1]) : (unsigned short)0;
            w[q * 4 + p] = (unsigned int)h0 | ((unsigned int)h1 << 16);
        }
    }
    size_t base = ((size_t)(m_blk * S + s) * 64) * 8;
    *(uint4*)&dst[base + (size_t)(0 * 32 + mrow) * 8] = make_uint4(w[0], w[1], w[2], w[3]);
    *(uint4*)&dst[base + (size_t)(1 * 32 + mrow) * 8] = make_uint4(w[4], w[5], w[6], w[7]);
}

__global__ void __launch_bounds__(256)
pack_b(const float* __restrict__ src1, const float* __restrict__ src2,
       unsigned short* __restrict__ dst, int K1, int S1, int K2, int SB)
{
    int g = blockIdx.x * 256 + threadIdx.x;
    if (g >= 10 * SB * 64) return;
    int lane = g & 63;
    int t = g >> 6;
    int s = t % SB;
    int n_blk = t / SB;
    int n = n_blk * 32 + (lane & 31);
    unsigned int w[4];
#pragma unroll
    for (int p = 0; p < 4; ++p) {
        unsigned short h[2];
#pragma unroll
        for (int e = 0; e < 2; ++e) {
            int kf = s * 16 + (lane >> 5) * 8 + p * 2 + e;
            float v = 0.0f;
            if (n < H) {
                if (s < S1) {
                    if (kf < K1) v = src1[(size_t)kf * H + n];
                } else {
                    int k2 = kf - S1 * 16;
                    if (k2 < K2) v = src2[(size_t)k2 * H + n];
                }
            }
            h[e] = f2bf(v);
        }
        w[p] = (unsigned int)h[0] | ((unsigned int)h[1] << 16);
    }
    *(uint4*)&dst[(size_t)g * 8] = make_uint4(w[0], w[1], w[2], w[3]);
}

// ---------------------------------------------------------------------------
// amsg[a][:] = sum_j msg[a2b[a][j]][:]; one thread per 8 halfs (38 groups/row).
// Pads [300,304) come out zero automatically (msg pads are zero).
__global__ void __launch_bounds__(256)
aggregate_row(const unsigned short* __restrict__ msg, const int* __restrict__ a2b,
              unsigned short* __restrict__ amsg, int n_atoms)
{
    int gid = blockIdx.x * 256 + threadIdx.x;
    int total = n_atoms * 38;
    if (gid >= total) return;
    int atom = gid / 38;
    int g8 = gid - atom * 38;
    const int* nb = a2b + atom * MAXNB;
    float sum[8] = {};
#pragma unroll
    for (int j = 0; j < MAXNB; ++j) {
        int b = nb[j];
        uint4 v = *(const uint4*)&msg[(size_t)b * RS + g8 * 8];
        unsigned int ww[4] = {v.x, v.y, v.z, v.w};
#pragma unroll
        for (int p = 0; p < 4; ++p) {
            sum[p * 2]     += bf2f((unsigned short)(ww[p] & 0xFFFFu));
            sum[p * 2 + 1] += bf2f((unsigned short)(ww[p] >> 16));
        }
    }
    unsigned int ow[4];
#pragma unroll
    for (int p = 0; p < 4; ++p)
        ow[p] = (unsigned int)f2bf(sum[p * 2]) | ((unsigned int)f2bf(sum[p * 2 + 1]) << 16);
    *(uint4*)&amsg[(size_t)atom * RS + g8 * 8] = make_uint4(ow[0], ow[1], ow[2], ow[3]);
}

// ---------------------------------------------------------------------------
// Fused MFMA GEMM with software-pipelined K-loop.
// MODE 0 (init): A = A1 packed only (S2 = 0).
// MODE 1 (mp):   A = [A1 packed | amsg[b2a[m]] - msg[b2revb[m]] (in-loop gather)]
//                out = relu(A @ B)   (the W_i/inp term is folded into A1/B stacking)
// MODE 2 (cat):  A = [A1 packed | amsg[m] direct rows]; out = relu(A @ B + bias)
// B packed with layout SBL steps. STOT = S1 + S2 steps actually executed.
template<int S1, int S2, int SBL, int MODE>
__global__ void __launch_bounds__(256)
gemm_fused(const unsigned short* __restrict__ A1,
           const unsigned short* __restrict__ amsg,
           const unsigned short* __restrict__ msg,
           const int* __restrict__ b2a, const int* __restrict__ b2revb,
           const unsigned short* __restrict__ Bp,
           const float* __restrict__ bias,
           unsigned short* __restrict__ out, int M)
{
    __shared__ unsigned short Cs[64][308];

    const int lane  = threadIdx.x & 63;
    const int w     = threadIdx.x >> 6;
    const int rbase = (w >> 1) * 32;
    const int cbase = (w & 1) * 160;
    const int mrow  = lane & 31;
    const int quad  = lane >> 5;
    const int m0    = blockIdx.x * 64;
    const int m_blk = blockIdx.x * 2 + (w >> 1);
    const int nblk0 = cbase >> 5;

    const int m  = m_blk * 32 + mrow;
    const int mv = (m < M) ? m : (M - 1);

    const unsigned short* pa1 = A1 + ((size_t)m_blk * S1 * 64 + lane) * 8;
    const unsigned short* pga = nullptr;
    const unsigned short* pgm = nullptr;
    if (MODE == 1) {
        pga = amsg + (size_t)b2a[mv] * RS + quad * 8;
        pgm = msg  + (size_t)b2revb[mv] * RS + quad * 8;
    } else if (MODE == 2) {
        pga = amsg + (size_t)mv * RS + quad * 8;
    }
    const unsigned short* pb = Bp + ((size_t)nblk0 * SBL * 64 + lane) * 8;

    f32x16 acc[5];
#pragma unroll
    for (int t = 0; t < 5; ++t)
#pragma unroll
        for (int i = 0; i < 16; ++i) acc[t][i] = 0.0f;

    constexpr int STOT = S1 + S2;

    bf16x8 aN{};
    uint4 vaN{}, vmN{};
    bf16x8 bN0{}, bN1{}, bN2{}, bN3{}, bN4{};

    auto issue = [&](int s) {
        bN0 = *(const bf16x8*)(pb + (size_t)(0 * SBL + s) * 512);
        bN1 = *(const bf16x8*)(pb + (size_t)(1 * SBL + s) * 512);
        bN2 = *(const bf16x8*)(pb + (size_t)(2 * SBL + s) * 512);
        bN3 = *(const bf16x8*)(pb + (size_t)(3 * SBL + s) * 512);
        bN4 = *(const bf16x8*)(pb + (size_t)(4 * SBL + s) * 512);
        if (s < S1) {
            aN = *(const bf16x8*)(pa1 + (size_t)s * 512);
        } else {
            int s2 = s - S1;
            if (MODE == 1) {
                vaN = *(const uint4*)(pga + s2 * 16);
                vmN = *(const uint4*)(pgm + s2 * 16);
            } else if (MODE == 2) {
                aN = *(const bf16x8*)(pga + s2 * 16);
            }
        }
    };

    issue(0);
#pragma unroll
    for (int s = 0; s < STOT; ++s) {
        bf16x8 aC = aN;
        uint4 vaC = vaN, vmC = vmN;
        bf16x8 bC0 = bN0, bC1 = bN1, bC2 = bN2, bC3 = bN3, bC4 = bN4;
        if (s + 1 < STOT) issue(s + 1);
        bf16x8 a;
        if (MODE == 1 && s >= S1) a = subpack(vaC, vmC);
        else                      a = aC;
        acc[0] = __builtin_amdgcn_mfma_f32_32x32x16_bf16(a, bC0, acc[0], 0, 0, 0);
        acc[1] = __builtin_amdgcn_mfma_f32_32x32x16_bf16(a, bC1, acc[1], 0, 0, 0);
        acc[2] = __builtin_amdgcn_mfma_f32_32x32x16_bf16(a, bC2, acc[2], 0, 0, 0);
        acc[3] = __builtin_amdgcn_mfma_f32_32x32x16_bf16(a, bC3, acc[3], 0, 0, 0);
        acc[4] = __builtin_amdgcn_mfma_f32_32x32x16_bf16(a, bC4, acc[4], 0, 0, 0);
    }

    // Epilogue: C/D col = lane&31 (+tile), row = (reg&3)+8*(reg>>2)+4*quad (+rbase)
#pragma unroll
    for (int nt = 0; nt < 5; ++nt) {
        int col = cbase + nt * 32 + mrow;
#pragma unroll
        for (int r = 0; r < 16; ++r) {
            int row = rbase + (r & 3) + 8 * (r >> 2) + 4 * quad;
            float v = acc[nt][r];
            if (bias && col < H) v += bias[col];
            if (col < 308) Cs[row][col] = f2bf(fmaxf(v, 0.0f));
        }
    }
    __syncthreads();

    for (int idx = threadIdx.x; idx < 64 * 76; idx += 256) {
        int row = idx / 76;
        int gcol = idx - row * 76;
        int mm = m0 + row;
        if (mm < M) {
            uint2 val = *(const uint2*)&Cs[row][gcol * 4];
            *(uint2*)&out[(size_t)mm * RS + gcol * 4] = val;
        }
    }
}

// ---------------------------------------------------------------------------
__global__ void __launch_bounds__(128)
segmean_kernel(const unsigned short* __restrict__ ah,
               const int* __restrict__ mol_id, int n_atoms,
               float* __restrict__ out)
{
    int m = blockIdx.x;
    int lo = 0, hi = n_atoms;
    while (lo < hi) { int mid = (lo + hi) >> 1; if (mol_id[mid] < m) lo = mid + 1; else hi = mid; }
    int start = lo;
    hi = n_atoms;
    while (lo < hi) { int mid = (lo + hi) >> 1; if (mol_id[mid] < m + 1) lo = mid + 1; else hi = mid; }
    int end = lo;

    int c = threadIdx.x;
    float a0 = 0.f, a1 = 0.f, a2 = 0.f;
    for (int a = start; a < end; ++a) {
        const unsigned short* row = ah + (size_t)a * RS;
        a0 += bf2f(row[c]);
        a1 += bf2f(row[c + 128]);
        if (c < H - 256) a2 += bf2f(row[c + 256]);
    }
    float inv = (end > start) ? 1.0f / (float)(end - start) : 0.0f;
    float* orow = out + (size_t)m * H;
    orow[c] = a0 * inv;
    orow[c + 128] = a1 * inv;
    if (c < H - 256) orow[c + 256] = a2 * inv;
}

// ---------------------------------------------------------------------------
extern "C" void kernel_launch(void* const* d_in, const int* in_sizes, int n_in,
                              void* d_out, int out_size, void* d_ws, size_t ws_size,
                              hipStream_t stream)
{
    const float* f_atoms = (const float*)d_in[0];
    const float* f_bonds = (const float*)d_in[1];
    const int*   a2b     = (const int*)d_in[2];
    const int*   b2a     = (const int*)d_in[3];
    const int*   b2revb  = (const int*)d_in[4];
    const int*   mol_id  = (const int*)d_in[5];
    const float* W_i     = (const float*)d_in[7];
    const float* W_h     = (const float*)d_in[8];
    const float* W_o     = (const float*)d_in[9];
    const float* b_o     = (const float*)d_in[10];

    const int n_atoms   = in_sizes[5];
    const int n_bonds   = in_sizes[3];
    const int atom_fdim = in_sizes[0] / n_atoms;   // 133
    const int bond_fdim = in_sizes[1] / n_bonds;   // 147
    const int n_mols    = out_size / H;            // 2000

    const int gBonds = (n_bonds + 63) / 64;        // 1563
    const int gAtoms = (n_atoms + 63) / 64;        // 782
    const int MBb = 2 * gBonds;
    const int MBa = 2 * gAtoms;

    // Workspace (halfs): msgA | msgB | amsg | fbp | fap | wih | wo  (~199 MB)
    unsigned short* msgA = (unsigned short*)d_ws;                    // n_bonds*RS
    unsigned short* msgB = msgA + (size_t)n_bonds * RS;              // n_bonds*RS
    unsigned short* amsg = msgB + (size_t)n_bonds * RS;              // n_atoms*RS
    unsigned short* fbp  = amsg + (size_t)n_atoms * RS;              // MBb*10*512
    unsigned short* fap  = fbp  + (size_t)MBb * 10 * 512;            // MBa*9*512
    unsigned short* wih  = fap  + (size_t)MBa * 9 * 512;             // 10*30*512
    unsigned short* wo   = wih  + 10 * 30 * 512;                     // 10*29*512
    unsigned short* ah   = fbp;   // atom_hiddens overlays fbp (free after mp#2)

    dim3 blk(256);

    // Weight packs: wih = [[W_i (147 rows, 10 steps)];[W_h (300 rows)]], SB=30
    pack_b<<<(10 * 30 * 64 + 255) / 256, blk, 0, stream>>>(W_i, W_h, wih, bond_fdim, 10, H, 30);
    // wo = [[W_o rows 0..132 (9 steps)];[W_o rows 133..432]], SB=29
    pack_b<<<(10 * 29 * 64 + 255) / 256, blk, 0, stream>>>(W_o, W_o + (size_t)atom_fdim * H, wo,
                                                           atom_fdim, 9, H, 29);
    pack_a_f32<<<(MBb * 10 * 32 + 255) / 256, blk, 0, stream>>>(f_bonds, fbp, n_bonds, bond_fdim, 10, MBb);
    pack_a_f32<<<(MBa * 9 * 32 + 255) / 256, blk, 0, stream>>>(f_atoms, fap, n_atoms, atom_fdim, 9, MBa);

    const int aggBlocks = (n_atoms * 38 + 255) / 256;

    // init: msgA = relu(f_bonds @ W_i)
    gemm_fused<10, 0, 30, 0><<<gBonds, blk, 0, stream>>>(
        fbp, nullptr, nullptr, nullptr, nullptr, wih, nullptr, msgA, n_bonds);

    // iter 1: msgA -> msgB   (gather fused into GEMM A-path; skip all-zero step)
    aggregate_row<<<aggBlocks, blk, 0, stream>>>(msgA, a2b, amsg, n_atoms);
    gemm_fused<10, 19, 30, 1><<<gBonds, blk, 0, stream>>>(
        fbp, amsg, msgA, b2a, b2revb, wih, nullptr, msgB, n_bonds);

    // iter 2: msgB -> msgA
    aggregate_row<<<aggBlocks, blk, 0, stream>>>(msgB, a2b, amsg, n_atoms);
    gemm_fused<10, 19, 30, 1><<<gBonds, blk, 0, stream>>>(
        fbp, amsg, msgB, b2a, b2revb, wih, nullptr, msgA, n_bonds);

    // final aggregation
    aggregate_row<<<aggBlocks, blk, 0, stream>>>(msgA, a2b, amsg, n_atoms);

    // cat GEMM: ah = relu([f_atoms | amsg] @ W_o + b_o)  (amsg rows read direct)
    gemm_fused<9, 19, 29, 2><<<gAtoms, blk, 0, stream>>>(
        fap, amsg, nullptr, nullptr, nullptr, wo, b_o, ah, n_atoms);

    segmean_kernel<<<n_mols, dim3(128), 0, stream>>>(ah, mol_id, n_atoms, (float*)d_out);
}